// Round 13
// baseline (194.942 us; speedup 1.0000x reference)
//
#include <hip/hip_runtime.h>

// HashLoss: contrastive (logsumexp over ln@ln^T/0.2) + 0.5*MSE(H@H^T/128, Tn@Tn^T)
//         + 0.01*mean||logits|-1|
// B=4096. R13 = R12 algebra (trace-identity distill on C=Q^T Q from QT fp8;
// S full-square ln-gram) with a BARRIER-FREE mega:
//  - S-role (1024 blocks, 128x128): MFMA frags loaded DIRECT from global P
//    (1 MB, L2-resident; 16-row x 64B coalesced), mask bytes direct per-lane,
//    per-quad shuffle + direct atomics. No LDS, no __syncthreads.
//  - D-role (105 blocks, 64x64 over 14x14 triangle): per-wave K=1024 slab
//    direct from QT (3.5 MB, L2-fits), one LDS combine round (stride-65 pad),
//    square-sum -> one relaxed atomicAdd(dtot).
// NO fences/acquire/release in hot kernels (R4/R8 lesson). 3 dispatches.

typedef __bf16 bf16x8 __attribute__((ext_vector_type(8)));
typedef float f32x4 __attribute__((ext_vector_type(4)));

__device__ __forceinline__ unsigned short f2bf(float f) {
  union { float f; unsigned int u; } v; v.f = f;
  unsigned int u = v.u;
  return (unsigned short)((u + 0x7FFFu + ((u >> 16) & 1u)) >> 16);  // RNE
}

// ---- prep: 256 blocks x 256 threads, 16 rows each (R12-proven).
__global__ __launch_bounds__(256) void prep(const float* __restrict__ logits,
                                            const float* __restrict__ hash,
                                            const float* __restrict__ teacher,
                                            unsigned short* __restrict__ P,
                                            unsigned char* __restrict__ QT,
                                            float* __restrict__ qpart,
                                            float* __restrict__ rowexp,
                                            float* __restrict__ possum,
                                            float* __restrict__ cntw,
                                            float* __restrict__ dtot) {
  __shared__ float rnt[16];
  __shared__ unsigned char QL[16 * 897];  // odd pitch: bank-spread col gathers
  const int t = threadIdx.x, wave = t >> 6, lane = t & 63;
  const int r0 = (int)blockIdx.x * 16;

#pragma unroll
  for (int rr = 0; rr < 4; ++rr) {
    const int rl = wave * 4 + rr, r = r0 + rl;
    float ss = 0.f;
#pragma unroll
    for (int i = 0; i < 12; ++i) {
      const float v = teacher[(size_t)r * 768 + i * 64 + lane];
      ss += v * v;
    }
    const float l0 = logits[(size_t)r * 128 + lane];
    const float l1 = logits[(size_t)r * 128 + 64 + lane];
    float ssl = l0 * l0 + l1 * l1;
    float qv = fabsf(fabsf(l0) - 1.f) + fabsf(fabsf(l1) - 1.f);
#pragma unroll
    for (int off = 1; off < 64; off <<= 1) {
      ss += __shfl_xor(ss, off, 64);
      ssl += __shfl_xor(ssl, off, 64);
      qv += __shfl_xor(qv, off, 64);
    }
    const float rnl = 1.f / fmaxf(sqrtf(ssl), 1e-12f);
    P[(size_t)r * 128 + lane] = f2bf(l0 * rnl);
    P[(size_t)r * 128 + 64 + lane] = f2bf(l1 * rnl);
    if (lane == 0) {
      rnt[rl] = 11.313708498984761f / fmaxf(sqrtf(ss), 1e-12f);  // sqrt128/||t||
      qpart[r] = qv;
    }
  }
  if (t < 16) { rowexp[r0 + t] = 0.f; possum[r0 + t] = 0.f; cntw[r0 + t] = 0.f; }
  if (blockIdx.x == 0 && t == 0) *dtot = 0.f;
  __syncthreads();

  // B: task = (row, 16-col block). 16 rows x 56 blocks = 896 tasks.
#pragma unroll
  for (int it = 0; it < 4; ++it) {
    const int task = it * 256 + t;
    if (task < 896) {
      const int r = task / 56, cb = task % 56;
      const int r_g = r0 + r;
      unsigned char* dst = &QL[r * 897 + cb * 16];
      if (cb < 8) {  // hash cols 0..127: exact +-1.0 e4m3
        const float4 v0 = *(const float4*)&hash[(size_t)r_g * 128 + cb * 16];
        const float4 v1 = *(const float4*)&hash[(size_t)r_g * 128 + cb * 16 + 4];
        const float4 v2 = *(const float4*)&hash[(size_t)r_g * 128 + cb * 16 + 8];
        const float4 v3 = *(const float4*)&hash[(size_t)r_g * 128 + cb * 16 + 12];
        const float vv[16] = {v0.x, v0.y, v0.z, v0.w, v1.x, v1.y, v1.z, v1.w,
                              v2.x, v2.y, v2.z, v2.w, v3.x, v3.y, v3.z, v3.w};
#pragma unroll
        for (int k = 0; k < 16; ++k) dst[k] = vv[k] >= 0.f ? 0x38 : 0xB8;
      } else {  // teacher cols: * sqrt(128)/||t||, fp8 e4m3
        const float sc = rnt[r];
        const int c0 = cb * 16 - 128;
        const float4 v0 = *(const float4*)&teacher[(size_t)r_g * 768 + c0];
        const float4 v1 = *(const float4*)&teacher[(size_t)r_g * 768 + c0 + 4];
        const float4 v2 = *(const float4*)&teacher[(size_t)r_g * 768 + c0 + 8];
        const float4 v3 = *(const float4*)&teacher[(size_t)r_g * 768 + c0 + 12];
        const float vv[16] = {v0.x, v0.y, v0.z, v0.w, v1.x, v1.y, v1.z, v1.w,
                              v2.x, v2.y, v2.z, v2.w, v3.x, v3.y, v3.z, v3.w};
#pragma unroll
        for (int k = 0; k < 16; ++k) {
          const int p8 = __builtin_amdgcn_cvt_pk_fp8_f32(vv[k] * sc, vv[k] * sc,
                                                         0, false);
          dst[k] = (unsigned char)(p8 & 0xFF);
        }
      }
    }
  }
  __syncthreads();

  // C: transpose-write. Thread owns column c: gather 16 rows, one 16B store.
#pragma unroll
  for (int i = 0; i < 4; ++i) {
    const int c = t + 256 * i;
    if (c < 896) {
      unsigned char buf[16];
#pragma unroll
      for (int j = 0; j < 16; ++j) buf[j] = QL[j * 897 + c];
      *(uint4*)&QT[(size_t)c * 4096 + r0] = *(uint4*)buf;
    }
  }
}

__global__ __launch_bounds__(256, 3) void mega(const unsigned short* __restrict__ P,
                                               const unsigned char* __restrict__ QT,
                                               const void* __restrict__ mask,
                                               float* __restrict__ rowexp,
                                               float* __restrict__ possum,
                                               float* __restrict__ cntw,
                                               float* __restrict__ dtot) {
  __shared__ float CD[3][64 * 65];  // D-role combine; stride-65 = bank-spread

  const int t = threadIdx.x;
  const int wave = t >> 6, lane = t & 63;
  const int qd = lane >> 4, l15 = lane & 15;
  const int b = (int)blockIdx.x;

  f32x4 acc[4][4];
#pragma unroll
  for (int rt = 0; rt < 4; ++rt)
#pragma unroll
    for (int ct = 0; ct < 4; ++ct) acc[rt][ct] = {0.f, 0.f, 0.f, 0.f};

  if (b < 105) {
    // ---- D-role: 64x64 tile (I,J) of C=Q^T Q over 14x14 triangle; wave owns
    // K-slab wave*1024..+1024, frags DIRECT from QT. One LDS combine round. --
    int I = 0, rem = b;
    while (rem >= 14 - I) { rem -= 14 - I; ++I; }
    const int J = I + rem;
    const unsigned char* Ab = QT + (size_t)(I * 64 + l15) * 4096 + wave * 1024 + qd * 8;
    const unsigned char* Bb = QT + (size_t)(J * 64 + l15) * 4096 + wave * 1024 + qd * 8;
#pragma unroll 4
    for (int ks = 0; ks < 32; ++ks) {
      long af[4], bfr[4];
#pragma unroll
      for (int rt = 0; rt < 4; ++rt)
        af[rt] = *(const long*)(Ab + (size_t)rt * 16 * 4096 + ks * 32);
#pragma unroll
      for (int ct = 0; ct < 4; ++ct)
        bfr[ct] = *(const long*)(Bb + (size_t)ct * 16 * 4096 + ks * 32);
#pragma unroll
      for (int rt = 0; rt < 4; ++rt)
#pragma unroll
        for (int ct = 0; ct < 4; ++ct)
          acc[rt][ct] = __builtin_amdgcn_mfma_f32_16x16x32_fp8_fp8(
              af[rt], bfr[ct], acc[rt][ct], 0, 0, 0);
    }
    // combine 4 waves' partial C then square-sum (must sum BEFORE squaring)
    if (wave != 0) {
      float* dstl = &CD[wave - 1][lane * 65];
#pragma unroll
      for (int rt = 0; rt < 4; ++rt)
#pragma unroll
        for (int ct = 0; ct < 4; ++ct)
#pragma unroll
          for (int i = 0; i < 4; ++i)
            dstl[rt * 16 + ct * 4 + i] = acc[rt][ct][i];
    }
    __syncthreads();
    if (wave == 0) {
      float dsum = 0.f;
#pragma unroll
      for (int rt = 0; rt < 4; ++rt)
#pragma unroll
        for (int ct = 0; ct < 4; ++ct)
#pragma unroll
          for (int i = 0; i < 4; ++i) {
            const int idx = lane * 65 + rt * 16 + ct * 4 + i;
            const float v = acc[rt][ct][i] + CD[0][idx] + CD[1][idx] + CD[2][idx];
            dsum += v * v;
          }
#pragma unroll
      for (int off = 1; off < 64; off <<= 1) dsum += __shfl_xor(dsum, off, 64);
      if (lane == 0) {
        const float mult = (I == J ? 1.f : 2.f) *
                           (((I < 2) == (J < 2)) ? 1.f : -1.f);
        atomicAdd(dtot, mult * dsum);
      }
    }
  } else {
    // ---- S-role: ln gram (bf16) 128x128 full-square, BARRIER-FREE ----
    const int bb = b - 105;
    const int l = (bb & 7) * 128 + (bb >> 3);  // XCD swizzle (1024 = 8*128)
    const int bi = l >> 5, bj = l & 31;
    const int ti = bi * 128, tj = bj * 128;
    const int wy = wave >> 1, wx = wave & 1;

    const unsigned short* Ab = P + (size_t)(ti + wy * 64 + l15) * 128 + qd * 8;
    const unsigned short* Bb = P + (size_t)(tj + wx * 64 + l15) * 128 + qd * 8;
#pragma unroll
    for (int ks = 0; ks < 4; ++ks) {
      bf16x8 af[4], bfr[4];
#pragma unroll
      for (int rt = 0; rt < 4; ++rt)
        af[rt] = *(const bf16x8*)(Ab + rt * 16 * 128 + ks * 32);
#pragma unroll
      for (int ct = 0; ct < 4; ++ct)
        bfr[ct] = *(const bf16x8*)(Bb + ct * 16 * 128 + ks * 32);
#pragma unroll
      for (int rt = 0; rt < 4; ++rt)
#pragma unroll
        for (int ct = 0; ct < 4; ++ct)
          acc[rt][ct] = __builtin_amdgcn_mfma_f32_16x16x32_bf16(
              af[rt], bfr[ct], acc[rt][ct], 0, 0, 0);
    }

    // epilogue: exp/logsumexp + sparse positives, mask read direct per-lane
    const unsigned char* m8 = (const unsigned char*)mask;
    const unsigned int* m32 = (const unsigned int*)mask;
    // byte 4097 = element (1,1) diag (1) if u8 layout; high byte (0) if i32.
    const bool is_byte = m8[4097] != 0;
#pragma unroll
    for (int rt = 0; rt < 4; ++rt) {
#pragma unroll
      for (int r = 0; r < 4; ++r) {
        const int m = ti + wy * 64 + rt * 16 + qd * 4 + r;  // C/D row map
        float se = 0.f;
#pragma unroll
        for (int ct = 0; ct < 4; ++ct) {
          const int n = tj + wx * 64 + ct * 16 + l15;       // C/D col map
          const float sim = acc[rt][ct][r] * 5.0f;          // /TEMPERATURE
          const float e = __expf(sim);
          if (m != n) se += e;                              // diag excluded
          const bool pm = is_byte ? (m8[(size_t)m * 4096 + n] != 0)
                                  : (m32[(size_t)m * 4096 + n] != 0);
          if (pm) {                                         // sparse positives
            atomicAdd(&possum[m], sim);
            atomicAdd(&cntw[m], 1.0f);
          }
        }
#pragma unroll
        for (int off = 1; off < 16; off <<= 1) se += __shfl_xor(se, off, 64);
        if (l15 == 0) atomicAdd(&rowexp[m], se);
      }
    }
  }
}

__global__ __launch_bounds__(1024) void finalize(const float* __restrict__ rowexp,
                                                 const float* __restrict__ possum,
                                                 const float* __restrict__ cnt,
                                                 const float* __restrict__ qpart,
                                                 const float* __restrict__ dtot,
                                                 float* __restrict__ out) {
  const int t = threadIdx.x;
  const int wave = t >> 6, lane = t & 63;
  float c = 0.f, q = 0.f;
  for (int m = t; m < 4096; m += 1024) {
    c += logf(rowexp[m]) - possum[m] / fmaxf(cnt[m], 1.0f);
    q += qpart[m];
  }
#pragma unroll
  for (int off = 1; off < 64; off <<= 1) {
    c += __shfl_xor(c, off, 64);
    q += __shfl_xor(q, off, 64);
  }
  __shared__ float sc[16], sq[16];
  if (lane == 0) { sc[wave] = c; sq[wave] = q; }
  __syncthreads();
  if (t == 0) {
    float C = 0.f, Q = 0.f;
    for (int i = 0; i < 16; ++i) { C += sc[i]; Q += sq[i]; }
    // dtot = 16384 * B^2 * loss_distill -> 0.5 * dtot / (4096^2 * 16384)
    out[0] = C * (1.0f / 4096.0f) + 0.5f * (dtot[0] * 3.6379788e-12f) +
             0.01f * (Q * (1.0f / 524288.0f));
  }
}

extern "C" void kernel_launch(void* const* d_in, const int* in_sizes, int n_in,
                              void* d_out, int out_size, void* d_ws, size_t ws_size,
                              hipStream_t stream) {
  const float* logits = (const float*)d_in[0];
  const float* hash = (const float*)d_in[1];
  const float* teacher = (const float*)d_in[2];
  const void* mask = d_in[3];
  float* out = (float*)d_out;

  char* ws = (char*)d_ws;
  float* rowexp = (float*)(ws + 0);
  float* possum = (float*)(ws + 16384);
  float* cntw = (float*)(ws + 32768);
  float* qpart = (float*)(ws + 49152);
  float* dtot = (float*)(ws + 65536);
  unsigned short* P = (unsigned short*)(ws + 98304);         // 4096x128 bf16 = 1 MB
  unsigned char* QT = (unsigned char*)(ws + 98304 + 1048576);  // 896x4096 fp8 = 3.5 MB

  prep<<<256, 256, 0, stream>>>(logits, hash, teacher, P, QT, qpart, rowexp,
                                possum, cntw, dtot);
  // 105 D-blocks (14x14 triangle, 64x64) + 1024 S-blocks (32x32 full, 128x128)
  mega<<<1129, 256, 0, stream>>>(P, QT, mask, rowexp, possum, cntw, dtot);
  finalize<<<1, 1024, 0, stream>>>(rowexp, possum, cntw, qpart, dtot, out);
}

// Round 14
// 159.249 us; speedup vs baseline: 1.2241x; 1.2241x over previous
//
#include <hip/hip_runtime.h>

// HashLoss: contrastive (logsumexp over ln@ln^T/0.2) + 0.5*MSE(H@H^T/128, Tn@Tn^T)
//         + 0.01*mean||logits|-1|
// B=4096. R14 = R12 (best: LDS-staged mega, trace-identity distill C=Q^T Q,
// 28 G-blocks full-K) with S-role back to TRIANGLE (528 blocks, mirror mask
// tile staged row-coalesced via global_load_lds -- R9-proven) to halve S work.
// NO fences/acquire/release in hot kernels (R4/R8 lesson). 3 dispatches.

typedef __bf16 bf16x8 __attribute__((ext_vector_type(8)));
typedef float f32x4 __attribute__((ext_vector_type(4)));

__device__ __forceinline__ unsigned short f2bf(float f) {
  union { float f; unsigned int u; } v; v.f = f;
  unsigned int u = v.u;
  return (unsigned short)((u + 0x7FFFu + ((u >> 16) & 1u)) >> 16);  // RNE
}

// ---- prep: 256 blocks x 256 threads, 16 rows each (R12-proven).
__global__ __launch_bounds__(256) void prep(const float* __restrict__ logits,
                                            const float* __restrict__ hash,
                                            const float* __restrict__ teacher,
                                            unsigned short* __restrict__ P,
                                            unsigned char* __restrict__ QT,
                                            float* __restrict__ qpart,
                                            float* __restrict__ rowexp,
                                            float* __restrict__ possum,
                                            float* __restrict__ cntw,
                                            float* __restrict__ dtot) {
  __shared__ float rnt[16];
  __shared__ unsigned char QL[16 * 897];  // odd pitch: bank-spread col gathers
  const int t = threadIdx.x, wave = t >> 6, lane = t & 63;
  const int r0 = (int)blockIdx.x * 16;

#pragma unroll
  for (int rr = 0; rr < 4; ++rr) {
    const int rl = wave * 4 + rr, r = r0 + rl;
    float ss = 0.f;
#pragma unroll
    for (int i = 0; i < 12; ++i) {
      const float v = teacher[(size_t)r * 768 + i * 64 + lane];
      ss += v * v;
    }
    const float l0 = logits[(size_t)r * 128 + lane];
    const float l1 = logits[(size_t)r * 128 + 64 + lane];
    float ssl = l0 * l0 + l1 * l1;
    float qv = fabsf(fabsf(l0) - 1.f) + fabsf(fabsf(l1) - 1.f);
#pragma unroll
    for (int off = 1; off < 64; off <<= 1) {
      ss += __shfl_xor(ss, off, 64);
      ssl += __shfl_xor(ssl, off, 64);
      qv += __shfl_xor(qv, off, 64);
    }
    const float rnl = 1.f / fmaxf(sqrtf(ssl), 1e-12f);
    P[(size_t)r * 128 + lane] = f2bf(l0 * rnl);
    P[(size_t)r * 128 + 64 + lane] = f2bf(l1 * rnl);
    if (lane == 0) {
      rnt[rl] = 11.313708498984761f / fmaxf(sqrtf(ss), 1e-12f);  // sqrt128/||t||
      qpart[r] = qv;
    }
  }
  if (t < 16) { rowexp[r0 + t] = 0.f; possum[r0 + t] = 0.f; cntw[r0 + t] = 0.f; }
  if (blockIdx.x == 0 && t == 0) *dtot = 0.f;
  __syncthreads();

  // B: task = (row, 16-col block). 16 rows x 56 blocks = 896 tasks.
#pragma unroll
  for (int it = 0; it < 4; ++it) {
    const int task = it * 256 + t;
    if (task < 896) {
      const int r = task / 56, cb = task % 56;
      const int r_g = r0 + r;
      unsigned char* dst = &QL[r * 897 + cb * 16];
      if (cb < 8) {  // hash cols 0..127: exact +-1.0 e4m3
        const float4 v0 = *(const float4*)&hash[(size_t)r_g * 128 + cb * 16];
        const float4 v1 = *(const float4*)&hash[(size_t)r_g * 128 + cb * 16 + 4];
        const float4 v2 = *(const float4*)&hash[(size_t)r_g * 128 + cb * 16 + 8];
        const float4 v3 = *(const float4*)&hash[(size_t)r_g * 128 + cb * 16 + 12];
        const float vv[16] = {v0.x, v0.y, v0.z, v0.w, v1.x, v1.y, v1.z, v1.w,
                              v2.x, v2.y, v2.z, v2.w, v3.x, v3.y, v3.z, v3.w};
#pragma unroll
        for (int k = 0; k < 16; ++k) dst[k] = vv[k] >= 0.f ? 0x38 : 0xB8;
      } else {  // teacher cols: * sqrt(128)/||t||, fp8 e4m3
        const float sc = rnt[r];
        const int c0 = cb * 16 - 128;
        const float4 v0 = *(const float4*)&teacher[(size_t)r_g * 768 + c0];
        const float4 v1 = *(const float4*)&teacher[(size_t)r_g * 768 + c0 + 4];
        const float4 v2 = *(const float4*)&teacher[(size_t)r_g * 768 + c0 + 8];
        const float4 v3 = *(const float4*)&teacher[(size_t)r_g * 768 + c0 + 12];
        const float vv[16] = {v0.x, v0.y, v0.z, v0.w, v1.x, v1.y, v1.z, v1.w,
                              v2.x, v2.y, v2.z, v2.w, v3.x, v3.y, v3.z, v3.w};
#pragma unroll
        for (int k = 0; k < 16; ++k) {
          const int p8 = __builtin_amdgcn_cvt_pk_fp8_f32(vv[k] * sc, vv[k] * sc,
                                                         0, false);
          dst[k] = (unsigned char)(p8 & 0xFF);
        }
      }
    }
  }
  __syncthreads();

  // C: transpose-write. Thread owns column c: gather 16 rows, one 16B store.
#pragma unroll
  for (int i = 0; i < 4; ++i) {
    const int c = t + 256 * i;
    if (c < 896) {
      unsigned char buf[16];
#pragma unroll
      for (int j = 0; j < 16; ++j) buf[j] = QL[j * 897 + c];
      *(uint4*)&QT[(size_t)c * 4096 + r0] = *(uint4*)buf;
    }
  }
}

// Stage 128 rows x 128 BYTES from gA (and gB if offdiag) into LDS bytes
// [0..16K) / [16K..32K). LDS 16B-slot p of row holds global chunk p^(row&7).
#define STAGE_GEN(GA, GB, PITCH)                                               \
  {                                                                            \
    _Pragma("unroll") for (int it = 0; it < 4; ++it) {                         \
      const int task = it * 256 + t;                                           \
      const int row = task >> 3;                                               \
      const int c16 = (task & 7) ^ (row & 7);                                  \
      const unsigned char* gpA = (GA) + (size_t)row * (PITCH) + c16 * 16;      \
      __builtin_amdgcn_global_load_lds(                                        \
          (const __attribute__((address_space(1))) void*)gpA,                  \
          (__attribute__((address_space(3))) void*)&SB[it * 4096 + wave * 1024],\
          16, 0, 0);                                                           \
      if (offdiag) {                                                           \
        const unsigned char* gpB = (GB) + (size_t)row * (PITCH) + c16 * 16;    \
        __builtin_amdgcn_global_load_lds(                                      \
            (const __attribute__((address_space(1))) void*)gpB,                \
            (__attribute__((address_space(3)))                                 \
                 void*)&SB[16384 + it * 4096 + wave * 1024],                   \
            16, 0, 0);                                                         \
      }                                                                        \
    }                                                                          \
  }

// bf16 chunk (64 cols = 2 ksteps), 16 MFMA each. Wave (wy,wx) owns 64x64 quad.
#define MFMA_B()                                                               \
  {                                                                            \
    _Pragma("unroll") for (int ks = 0; ks < 2; ++ks) {                         \
      const int ph = ((ks * 4 + qd) ^ (l15 & 7)) * 16;                         \
      bf16x8 af[4], bfr[4];                                                    \
      _Pragma("unroll") for (int rt = 0; rt < 4; ++rt)                         \
          af[rt] = *(const bf16x8*)&SB[(wy * 64 + rt * 16 + l15) * 128 + ph];  \
      _Pragma("unroll") for (int ct = 0; ct < 4; ++ct)                         \
          bfr[ct] = *(const bf16x8*)&SB[boffB +                                \
                                        (wx * 64 + ct * 16 + l15) * 128 + ph]; \
      _Pragma("unroll") for (int rt = 0; rt < 4; ++rt)                         \
          _Pragma("unroll") for (int ct = 0; ct < 4; ++ct) acc[rt][ct] =       \
          __builtin_amdgcn_mfma_f32_16x16x32_bf16(af[rt], bfr[ct],             \
                                                  acc[rt][ct], 0, 0, 0);       \
    }                                                                          \
  }

// fp8 chunk (128 cols = 4 ksteps), 16 MFMA each; 8B frags.
#define MFMA_Q()                                                               \
  {                                                                            \
    _Pragma("unroll") for (int ks = 0; ks < 4; ++ks) {                         \
      const int g0 = ks * 4 + qd;                                              \
      const int ph = ((g0 >> 1) ^ (l15 & 7)) * 16 + (g0 & 1) * 8;              \
      long af[4], bfr[4];                                                      \
      _Pragma("unroll") for (int rt = 0; rt < 4; ++rt)                         \
          af[rt] = *(const long*)&SB[(wy * 64 + rt * 16 + l15) * 128 + ph];    \
      _Pragma("unroll") for (int ct = 0; ct < 4; ++ct)                         \
          bfr[ct] = *(const long*)&SB[boffB +                                  \
                                      (wx * 64 + ct * 16 + l15) * 128 + ph];   \
      _Pragma("unroll") for (int rt = 0; rt < 4; ++rt)                         \
          _Pragma("unroll") for (int ct = 0; ct < 4; ++ct) acc[rt][ct] =       \
          __builtin_amdgcn_mfma_f32_16x16x32_fp8_fp8(af[rt], bfr[ct],          \
                                                     acc[rt][ct], 0, 0, 0);    \
    }                                                                          \
  }

__global__ __launch_bounds__(256, 3) void mega(const unsigned short* __restrict__ P,
                                               const unsigned char* __restrict__ QT,
                                               const void* __restrict__ mask,
                                               float* __restrict__ rowexp,
                                               float* __restrict__ possum,
                                               float* __restrict__ cntw,
                                               float* __restrict__ dtot) {
  __shared__ __align__(16) unsigned char SB[32768];  // A @0, B @16384
  __shared__ float redrow[128][2], redcol[128][2], red4[4];

  const int t = threadIdx.x;
  const int wave = t >> 6, lane = t & 63;
  const int qd = lane >> 4, l15 = lane & 15;
  const int wy = wave >> 1, wx = wave & 1;
  const int b = (int)blockIdx.x;

  f32x4 acc[4][4];
#pragma unroll
  for (int rt = 0; rt < 4; ++rt)
#pragma unroll
    for (int ct = 0; ct < 4; ++ct) acc[rt][ct] = {0.f, 0.f, 0.f, 0.f};

  if (b < 28) {
    // ---- G-role: C = Q^T Q tile (I,J) from QT, full K=4096 (32 chunks) ----
    int I = 0, rem = b;
    while (rem >= 7 - I) { rem -= 7 - I; ++I; }
    const int J = I + rem;
    const bool offdiag = (I != J);
    const int boffB = offdiag ? 16384 : 0;
    const unsigned char* QA = QT + (size_t)I * 128 * 4096;
    const unsigned char* QB = QT + (size_t)J * 128 * 4096;
    for (int kc = 0; kc < 32; ++kc) {
      __syncthreads();
      STAGE_GEN(QA + kc * 128, QB + kc * 128, 4096);
      __syncthreads();
      MFMA_Q();
    }
    // fused sign-weighted Frobenius (C/D lane layout irrelevant for a sum)
    float dsum = 0.f;
#pragma unroll
    for (int rt = 0; rt < 4; ++rt)
#pragma unroll
      for (int ct = 0; ct < 4; ++ct)
#pragma unroll
        for (int i = 0; i < 4; ++i) dsum += acc[rt][ct][i] * acc[rt][ct][i];
#pragma unroll
    for (int off = 1; off < 64; off <<= 1) dsum += __shfl_xor(dsum, off, 64);
    if (lane == 0) red4[wave] = dsum;
    __syncthreads();
    if (t == 0) {
      const float mult = (I == J ? 1.f : 2.f) *
                         (((I == 0) == (J == 0)) ? 1.f : -1.f);
      atomicAdd(dtot, mult * (red4[0] + red4[1] + red4[2] + red4[3]));
    }
  } else {
    // ---- S-role: ln gram (bf16), 128x128 TRIANGLE tile + mirror epilogue ---
    const int bb = b - 28;
    const int l = (bb & 7) * 66 + (bb >> 3);  // XCD swizzle (528 = 8*66)
    int bi = (int)((65.0f - sqrtf(4225.0f - 8.0f * (float)l)) * 0.5f);
    while (bi * (65 - bi) / 2 > l) --bi;
    while ((bi + 1) * (64 - bi) / 2 <= l) ++bi;
    const int bj = bi + (l - bi * (65 - bi) / 2);
    const int ti = bi * 128, tj = bj * 128;
    const bool offdiag = (bi != bj);
    const int boffB = offdiag ? 16384 : 0;

    const unsigned char* Pa = (const unsigned char*)(P + (size_t)ti * 128);
    const unsigned char* Pb = (const unsigned char*)(P + (size_t)tj * 128);
    for (int kc = 0; kc < 2; ++kc) {
      __syncthreads();
      STAGE_GEN(Pa + kc * 128, Pb + kc * 128, 256);
      __syncthreads();
      MFMA_B();
    }

    // ---- mask tiles -> LDS (direct + mirror, both row-coalesced) ----
    __syncthreads();
    unsigned char* MD = SB;          // [mrow][ncol], 16KB
    unsigned char* MM = SB + 16384;  // [ncol][mrow], 16KB
    const bool is_byte = ((const unsigned char*)mask)[4097] != 0;
    if (is_byte) {
      const unsigned char* m8d = (const unsigned char*)mask + (size_t)ti * 4096 + tj;
      const unsigned char* m8m = (const unsigned char*)mask + (size_t)tj * 4096 + ti;
#pragma unroll
      for (int it = 0; it < 4; ++it) {
        const int task = it * 256 + t;
        const int row = task >> 3, seg = task & 7;
        __builtin_amdgcn_global_load_lds(
            (const __attribute__((address_space(1))) void*)
                (m8d + (size_t)row * 4096 + seg * 16),
            (__attribute__((address_space(3))) void*)&MD[it * 4096 + wave * 1024],
            16, 0, 0);
        if (offdiag)
          __builtin_amdgcn_global_load_lds(
              (const __attribute__((address_space(1))) void*)
                  (m8m + (size_t)row * 4096 + seg * 16),
              (__attribute__((address_space(3))) void*)&MM[it * 4096 + wave * 1024],
              16, 0, 0);
      }
    } else {
      const unsigned int* m32 = (const unsigned int*)mask;
#pragma unroll
      for (int it = 0; it < 16; ++it) {
        const int task = it * 256 + t;
        const int row = task >> 5, seg = task & 31;
        const uint4 v = *(const uint4*)&m32[(size_t)(ti + row) * 4096 + tj + seg * 4];
        uchar4 pk;
        pk.x = v.x ? 1 : 0; pk.y = v.y ? 1 : 0;
        pk.z = v.z ? 1 : 0; pk.w = v.w ? 1 : 0;
        *(uchar4*)&MD[row * 128 + seg * 4] = pk;
        if (offdiag) {
          const uint4 w = *(const uint4*)&m32[(size_t)(tj + row) * 4096 + ti + seg * 4];
          uchar4 pm;
          pm.x = w.x ? 1 : 0; pm.y = w.y ? 1 : 0;
          pm.z = w.z ? 1 : 0; pm.w = w.w ? 1 : 0;
          *(uchar4*)&MM[row * 128 + seg * 4] = pm;
        }
      }
    }
    __syncthreads();

    float colp[4] = {0.f, 0.f, 0.f, 0.f};
#pragma unroll
    for (int rt = 0; rt < 4; ++rt) {
#pragma unroll
      for (int r = 0; r < 4; ++r) {
        const int mrow = wy * 64 + rt * 16 + qd * 4 + r;  // C/D: row=qd*4+reg
        const int m = ti + mrow;
        float se = 0.f;
#pragma unroll
        for (int ct = 0; ct < 4; ++ct) {
          const int ncol = wx * 64 + ct * 16 + l15;        // C/D: col=lane&15
          const int n = tj + ncol;
          const float sim = acc[rt][ct][r] * 5.0f;         // /TEMPERATURE
          const float e = __expf(sim);
          if (offdiag || mrow != ncol) se += e;            // diag excluded
          if (offdiag) colp[ct] += e;
          if (MD[mrow * 128 + ncol]) {                     // sparse positives
            atomicAdd(&possum[m], sim);
            atomicAdd(&cntw[m], 1.0f);
          }
          if (offdiag && MM[ncol * 128 + mrow]) {          // mirror (n, m)
            atomicAdd(&possum[n], sim);
            atomicAdd(&cntw[n], 1.0f);
          }
        }
#pragma unroll
        for (int off = 1; off < 16; off <<= 1) se += __shfl_xor(se, off, 64);
        if (l15 == 0) redrow[mrow][wx] = se;
      }
    }
    if (offdiag) {
#pragma unroll
      for (int ct = 0; ct < 4; ++ct) {
        float ce = colp[ct];
        ce += __shfl_xor(ce, 16, 64);
        ce += __shfl_xor(ce, 32, 64);
        if (qd == 0) redcol[wx * 64 + ct * 16 + l15][wy] = ce;
      }
    }
    __syncthreads();
    if (t < 128) {
      atomicAdd(&rowexp[ti + t], redrow[t][0] + redrow[t][1]);
      if (offdiag) atomicAdd(&rowexp[tj + t], redcol[t][0] + redcol[t][1]);
    }
  }
}

__global__ __launch_bounds__(1024) void finalize(const float* __restrict__ rowexp,
                                                 const float* __restrict__ possum,
                                                 const float* __restrict__ cnt,
                                                 const float* __restrict__ qpart,
                                                 const float* __restrict__ dtot,
                                                 float* __restrict__ out) {
  const int t = threadIdx.x;
  const int wave = t >> 6, lane = t & 63;
  float c = 0.f, q = 0.f;
  for (int m = t; m < 4096; m += 1024) {
    c += logf(rowexp[m]) - possum[m] / fmaxf(cnt[m], 1.0f);
    q += qpart[m];
  }
#pragma unroll
  for (int off = 1; off < 64; off <<= 1) {
    c += __shfl_xor(c, off, 64);
    q += __shfl_xor(q, off, 64);
  }
  __shared__ float sc[16], sq[16];
  if (lane == 0) { sc[wave] = c; sq[wave] = q; }
  __syncthreads();
  if (t == 0) {
    float C = 0.f, Q = 0.f;
    for (int i = 0; i < 16; ++i) { C += sc[i]; Q += sq[i]; }
    // dtot = 16384 * B^2 * loss_distill -> 0.5 * dtot / (4096^2 * 16384)
    out[0] = C * (1.0f / 4096.0f) + 0.5f * (dtot[0] * 3.6379788e-12f) +
             0.01f * (Q * (1.0f / 524288.0f));
  }
}

extern "C" void kernel_launch(void* const* d_in, const int* in_sizes, int n_in,
                              void* d_out, int out_size, void* d_ws, size_t ws_size,
                              hipStream_t stream) {
  const float* logits = (const float*)d_in[0];
  const float* hash = (const float*)d_in[1];
  const float* teacher = (const float*)d_in[2];
  const void* mask = d_in[3];
  float* out = (float*)d_out;

  char* ws = (char*)d_ws;
  float* rowexp = (float*)(ws + 0);
  float* possum = (float*)(ws + 16384);
  float* cntw = (float*)(ws + 32768);
  float* qpart = (float*)(ws + 49152);
  float* dtot = (float*)(ws + 65536);
  unsigned short* P = (unsigned short*)(ws + 98304);         // 4096x128 bf16 = 1 MB
  unsigned char* QT = (unsigned char*)(ws + 98304 + 1048576);  // 896x4096 fp8 = 3.5 MB

  prep<<<256, 256, 0, stream>>>(logits, hash, teacher, P, QT, qpart, rowexp,
                                possum, cntw, dtot);
  // 28 G-blocks (C=Q^T Q, 7x7 triangle) + 528 S-blocks (32x32 triangle)
  mega<<<556, 256, 0, stream>>>(P, QT, mask, rowexp, possum, cntw, dtot);
  finalize<<<1, 1024, 0, stream>>>(rowexp, possum, cntw, qpart, dtot, out);
}

// Round 15
// 155.782 us; speedup vs baseline: 1.2514x; 1.0223x over previous
//
#include <hip/hip_runtime.h>

// HashLoss: contrastive (logsumexp over ln@ln^T/0.2) + 0.5*MSE(H@H^T/128, Tn@Tn^T)
//         + 0.01*mean||logits|-1|
// B=4096. R15 = R12 (best) with ONE-SHOT S-role staging:
//  - S-role (1024 full-square 128x128 tiles): ln stored fp8 e4m3 (Pq, 512KB) ->
//    A(16KB)+B(16KB)+mask(16KB) staged in ONE round, ONE barrier, 64 fp8 MFMA.
//    (R12 paid 5 barrier-coupled DMA drains per S-block; this pays 1.)
//  - G-role (28 blocks): C=Q^T Q trace-identity distill, full K=4096, unchanged.
//  - prep: R12 structure; phase A now emits Pq fp8 (float2/lane + cvt_pk_fp8).
// NO fences/acquire/release in hot kernels (R4/R8 lesson). 3 dispatches.

typedef float f32x4 __attribute__((ext_vector_type(4)));

// ---- prep: 256 blocks x 256 threads, 16 rows each (R12-proven).
__global__ __launch_bounds__(256) void prep(const float* __restrict__ logits,
                                            const float* __restrict__ hash,
                                            const float* __restrict__ teacher,
                                            unsigned char* __restrict__ Pq,
                                            unsigned char* __restrict__ QT,
                                            float* __restrict__ qpart,
                                            float* __restrict__ rowexp,
                                            float* __restrict__ possum,
                                            float* __restrict__ cntw,
                                            float* __restrict__ dtot) {
  __shared__ float rnt[16];
  __shared__ unsigned char QL[16 * 897];  // odd pitch: bank-spread col gathers
  const int t = threadIdx.x, wave = t >> 6, lane = t & 63;
  const int r0 = (int)blockIdx.x * 16;

#pragma unroll
  for (int rr = 0; rr < 4; ++rr) {
    const int rl = wave * 4 + rr, r = r0 + rl;
    float ss = 0.f;
#pragma unroll
    for (int i = 0; i < 12; ++i) {
      const float v = teacher[(size_t)r * 768 + i * 64 + lane];
      ss += v * v;
    }
    const float2 lv = *(const float2*)&logits[(size_t)r * 128 + 2 * lane];
    float ssl = lv.x * lv.x + lv.y * lv.y;
    float qv = fabsf(fabsf(lv.x) - 1.f) + fabsf(fabsf(lv.y) - 1.f);
#pragma unroll
    for (int off = 1; off < 64; off <<= 1) {
      ss += __shfl_xor(ss, off, 64);
      ssl += __shfl_xor(ssl, off, 64);
      qv += __shfl_xor(qv, off, 64);
    }
    const float rnl = 1.f / fmaxf(sqrtf(ssl), 1e-12f);
    const int p8 = __builtin_amdgcn_cvt_pk_fp8_f32(lv.x * rnl, lv.y * rnl, 0, false);
    *(unsigned short*)&Pq[(size_t)r * 128 + 2 * lane] = (unsigned short)(p8 & 0xFFFF);
    if (lane == 0) {
      rnt[rl] = 11.313708498984761f / fmaxf(sqrtf(ss), 1e-12f);  // sqrt128/||t||
      qpart[r] = qv;
    }
  }
  if (t < 16) { rowexp[r0 + t] = 0.f; possum[r0 + t] = 0.f; cntw[r0 + t] = 0.f; }
  if (blockIdx.x == 0 && t == 0) *dtot = 0.f;
  __syncthreads();

  // B: task = (row, 16-col block). 16 rows x 56 blocks = 896 tasks.
#pragma unroll
  for (int it = 0; it < 4; ++it) {
    const int task = it * 256 + t;
    if (task < 896) {
      const int r = task / 56, cb = task % 56;
      const int r_g = r0 + r;
      unsigned char* dst = &QL[r * 897 + cb * 16];
      if (cb < 8) {  // hash cols 0..127: exact +-1.0 e4m3
        const float4 v0 = *(const float4*)&hash[(size_t)r_g * 128 + cb * 16];
        const float4 v1 = *(const float4*)&hash[(size_t)r_g * 128 + cb * 16 + 4];
        const float4 v2 = *(const float4*)&hash[(size_t)r_g * 128 + cb * 16 + 8];
        const float4 v3 = *(const float4*)&hash[(size_t)r_g * 128 + cb * 16 + 12];
        const float vv[16] = {v0.x, v0.y, v0.z, v0.w, v1.x, v1.y, v1.z, v1.w,
                              v2.x, v2.y, v2.z, v2.w, v3.x, v3.y, v3.z, v3.w};
#pragma unroll
        for (int k = 0; k < 16; ++k) dst[k] = vv[k] >= 0.f ? 0x38 : 0xB8;
      } else {  // teacher cols: * sqrt(128)/||t||, fp8 e4m3
        const float sc = rnt[r];
        const int c0 = cb * 16 - 128;
        const float4 v0 = *(const float4*)&teacher[(size_t)r_g * 768 + c0];
        const float4 v1 = *(const float4*)&teacher[(size_t)r_g * 768 + c0 + 4];
        const float4 v2 = *(const float4*)&teacher[(size_t)r_g * 768 + c0 + 8];
        const float4 v3 = *(const float4*)&teacher[(size_t)r_g * 768 + c0 + 12];
        const float vv[16] = {v0.x, v0.y, v0.z, v0.w, v1.x, v1.y, v1.z, v1.w,
                              v2.x, v2.y, v2.z, v2.w, v3.x, v3.y, v3.z, v3.w};
#pragma unroll
        for (int k = 0; k < 16; ++k) {
          const int p8 = __builtin_amdgcn_cvt_pk_fp8_f32(vv[k] * sc, vv[k] * sc,
                                                         0, false);
          dst[k] = (unsigned char)(p8 & 0xFF);
        }
      }
    }
  }
  __syncthreads();

  // C: transpose-write. Thread owns column c: gather 16 rows, one 16B store.
#pragma unroll
  for (int i = 0; i < 4; ++i) {
    const int c = t + 256 * i;
    if (c < 896) {
      unsigned char buf[16];
#pragma unroll
      for (int j = 0; j < 16; ++j) buf[j] = QL[j * 897 + c];
      *(uint4*)&QT[(size_t)c * 4096 + r0] = *(uint4*)buf;
    }
  }
}

// Stage 128 rows x 128 BYTES from gA (and gB if offdiag) into LDS bytes
// [0..16K) / [16K..32K). LDS 16B-slot p of row holds global chunk p^(row&7).
#define STAGE_GEN(GA, GB, PITCH)                                               \
  {                                                                            \
    _Pragma("unroll") for (int it = 0; it < 4; ++it) {                         \
      const int task = it * 256 + t;                                           \
      const int row = task >> 3;                                               \
      const int c16 = (task & 7) ^ (row & 7);                                  \
      const unsigned char* gpA = (GA) + (size_t)row * (PITCH) + c16 * 16;      \
      __builtin_amdgcn_global_load_lds(                                        \
          (const __attribute__((address_space(1))) void*)gpA,                  \
          (__attribute__((address_space(3))) void*)&SB[it * 4096 + wave * 1024],\
          16, 0, 0);                                                           \
      if (offdiag) {                                                           \
        const unsigned char* gpB = (GB) + (size_t)row * (PITCH) + c16 * 16;    \
        __builtin_amdgcn_global_load_lds(                                      \
            (const __attribute__((address_space(1))) void*)gpB,                \
            (__attribute__((address_space(3)))                                 \
                 void*)&SB[16384 + it * 4096 + wave * 1024],                   \
            16, 0, 0);                                                         \
      }                                                                        \
    }                                                                          \
  }

// fp8 chunk (128 cols = 4 ksteps), 16 MFMA each; 8B frags.
#define MFMA_Q()                                                               \
  {                                                                            \
    _Pragma("unroll") for (int ks = 0; ks < 4; ++ks) {                         \
      const int g0 = ks * 4 + qd;                                              \
      const int ph = ((g0 >> 1) ^ (l15 & 7)) * 16 + (g0 & 1) * 8;              \
      long af[4], bfr[4];                                                      \
      _Pragma("unroll") for (int rt = 0; rt < 4; ++rt)                         \
          af[rt] = *(const long*)&SB[(wy * 64 + rt * 16 + l15) * 128 + ph];    \
      _Pragma("unroll") for (int ct = 0; ct < 4; ++ct)                         \
          bfr[ct] = *(const long*)&SB[boffB +                                  \
                                      (wx * 64 + ct * 16 + l15) * 128 + ph];   \
      _Pragma("unroll") for (int rt = 0; rt < 4; ++rt)                         \
          _Pragma("unroll") for (int ct = 0; ct < 4; ++ct) acc[rt][ct] =       \
          __builtin_amdgcn_mfma_f32_16x16x32_fp8_fp8(af[rt], bfr[ct],          \
                                                     acc[rt][ct], 0, 0, 0);    \
    }                                                                          \
  }

__global__ __launch_bounds__(256, 3) void mega(const unsigned char* __restrict__ Pq,
                                               const unsigned char* __restrict__ QT,
                                               const void* __restrict__ mask,
                                               float* __restrict__ rowexp,
                                               float* __restrict__ possum,
                                               float* __restrict__ cntw,
                                               float* __restrict__ dtot) {
  __shared__ __align__(16) unsigned char SB[49152];  // A@0, B@16K, mask MD@32K
  __shared__ float redrow[128][2], red4[4];

  const int t = threadIdx.x;
  const int wave = t >> 6, lane = t & 63;
  const int qd = lane >> 4, l15 = lane & 15;
  const int wy = wave >> 1, wx = wave & 1;
  const int b = (int)blockIdx.x;

  f32x4 acc[4][4];
#pragma unroll
  for (int rt = 0; rt < 4; ++rt)
#pragma unroll
    for (int ct = 0; ct < 4; ++ct) acc[rt][ct] = {0.f, 0.f, 0.f, 0.f};

  if (b < 28) {
    // ---- G-role: C = Q^T Q tile (I,J) from QT, full K=4096 (32 chunks) ----
    int I = 0, rem = b;
    while (rem >= 7 - I) { rem -= 7 - I; ++I; }
    const int J = I + rem;
    const bool offdiag = (I != J);
    const int boffB = offdiag ? 16384 : 0;
    const unsigned char* QA = QT + (size_t)I * 128 * 4096;
    const unsigned char* QB = QT + (size_t)J * 128 * 4096;
    for (int kc = 0; kc < 32; ++kc) {
      __syncthreads();
      STAGE_GEN(QA + kc * 128, QB + kc * 128, 4096);
      __syncthreads();
      MFMA_Q();
    }
    // fused sign-weighted Frobenius (C/D lane layout irrelevant for a sum)
    float dsum = 0.f;
#pragma unroll
    for (int rt = 0; rt < 4; ++rt)
#pragma unroll
      for (int ct = 0; ct < 4; ++ct)
#pragma unroll
        for (int i = 0; i < 4; ++i) dsum += acc[rt][ct][i] * acc[rt][ct][i];
#pragma unroll
    for (int off = 1; off < 64; off <<= 1) dsum += __shfl_xor(dsum, off, 64);
    if (lane == 0) red4[wave] = dsum;
    __syncthreads();
    if (t == 0) {
      const float mult = (I == J ? 1.f : 2.f) *
                         (((I == 0) == (J == 0)) ? 1.f : -1.f);
      atomicAdd(dtot, mult * (red4[0] + red4[1] + red4[2] + red4[3]));
    }
  } else {
    // ---- S-role: ln gram (fp8), FULL-square 128x128, ONE staging round ----
    const int bb = b - 28;
    const int l = (bb & 7) * 128 + (bb >> 3);  // XCD swizzle (1024 = 8*128)
    const int bi = l >> 5, bj = l & 31;
    const int ti = bi * 128, tj = bj * 128;
    const bool offdiag = (bi != bj);           // diag tile: B = A (boffB 0)
    const int boffB = offdiag ? 16384 : 0;

    // issue A+B fp8 tiles (full K=128 each) ...
    STAGE_GEN(Pq + (size_t)ti * 128, Pq + (size_t)tj * 128, 128);
    // ... and the mask row-tile, all drained by ONE barrier.
    unsigned char* MD = SB + 32768;  // [mrow][ncol], 16KB
    const bool is_byte = ((const unsigned char*)mask)[4097] != 0;
    if (is_byte) {
      const unsigned char* m8d = (const unsigned char*)mask + (size_t)ti * 4096 + tj;
#pragma unroll
      for (int it = 0; it < 4; ++it) {
        const int task = it * 256 + t;
        const int row = task >> 3, seg = task & 7;
        __builtin_amdgcn_global_load_lds(
            (const __attribute__((address_space(1))) void*)
                (m8d + (size_t)row * 4096 + seg * 16),
            (__attribute__((address_space(3))) void*)&MD[it * 4096 + wave * 1024],
            16, 0, 0);
      }
    } else {
      const unsigned int* m32 = (const unsigned int*)mask;
#pragma unroll
      for (int it = 0; it < 16; ++it) {
        const int task = it * 256 + t;
        const int row = task >> 5, seg = task & 31;
        const uint4 v = *(const uint4*)&m32[(size_t)(ti + row) * 4096 + tj + seg * 4];
        uchar4 pk;
        pk.x = v.x ? 1 : 0; pk.y = v.y ? 1 : 0;
        pk.z = v.z ? 1 : 0; pk.w = v.w ? 1 : 0;
        *(uchar4*)&MD[row * 128 + seg * 4] = pk;
      }
    }
    __syncthreads();

    MFMA_Q();  // 4 ksteps x 16 MFMA: full K=128 gram

#pragma unroll
    for (int rt = 0; rt < 4; ++rt) {
#pragma unroll
      for (int r = 0; r < 4; ++r) {
        const int mrow = wy * 64 + rt * 16 + qd * 4 + r;  // C/D: row=qd*4+reg
        const int m = ti + mrow;
        float se = 0.f;
#pragma unroll
        for (int ct = 0; ct < 4; ++ct) {
          const int ncol = wx * 64 + ct * 16 + l15;       // C/D: col=lane&15
          const int n = tj + ncol;
          const float sim = acc[rt][ct][r] * 5.0f;        // /TEMPERATURE
          const float e = __expf(sim);
          if (m != n) se += e;                            // diag excluded
          if (MD[mrow * 128 + ncol]) {                    // sparse positives
            atomicAdd(&possum[m], sim);
            atomicAdd(&cntw[m], 1.0f);
          }
        }
#pragma unroll
        for (int off = 1; off < 16; off <<= 1) se += __shfl_xor(se, off, 64);
        if (l15 == 0) redrow[mrow][wx] = se;
      }
    }
    __syncthreads();
    if (t < 128) atomicAdd(&rowexp[ti + t], redrow[t][0] + redrow[t][1]);
  }
}

__global__ __launch_bounds__(1024) void finalize(const float* __restrict__ rowexp,
                                                 const float* __restrict__ possum,
                                                 const float* __restrict__ cnt,
                                                 const float* __restrict__ qpart,
                                                 const float* __restrict__ dtot,
                                                 float* __restrict__ out) {
  const int t = threadIdx.x;
  const int wave = t >> 6, lane = t & 63;
  float c = 0.f, q = 0.f;
  for (int m = t; m < 4096; m += 1024) {
    c += logf(rowexp[m]) - possum[m] / fmaxf(cnt[m], 1.0f);
    q += qpart[m];
  }
#pragma unroll
  for (int off = 1; off < 64; off <<= 1) {
    c += __shfl_xor(c, off, 64);
    q += __shfl_xor(q, off, 64);
  }
  __shared__ float sc[16], sq[16];
  if (lane == 0) { sc[wave] = c; sq[wave] = q; }
  __syncthreads();
  if (t == 0) {
    float C = 0.f, Q = 0.f;
    for (int i = 0; i < 16; ++i) { C += sc[i]; Q += sq[i]; }
    // dtot = 16384 * B^2 * loss_distill -> 0.5 * dtot / (4096^2 * 16384)
    out[0] = C * (1.0f / 4096.0f) + 0.5f * (dtot[0] * 3.6379788e-12f) +
             0.01f * (Q * (1.0f / 524288.0f));
  }
}

extern "C" void kernel_launch(void* const* d_in, const int* in_sizes, int n_in,
                              void* d_out, int out_size, void* d_ws, size_t ws_size,
                              hipStream_t stream) {
  const float* logits = (const float*)d_in[0];
  const float* hash = (const float*)d_in[1];
  const float* teacher = (const float*)d_in[2];
  const void* mask = d_in[3];
  float* out = (float*)d_out;

  char* ws = (char*)d_ws;
  float* rowexp = (float*)(ws + 0);
  float* possum = (float*)(ws + 16384);
  float* cntw = (float*)(ws + 32768);
  float* qpart = (float*)(ws + 49152);
  float* dtot = (float*)(ws + 65536);
  unsigned char* Pq = (unsigned char*)(ws + 98304);           // 4096x128 fp8 = 512KB
  unsigned char* QT = (unsigned char*)(ws + 98304 + 1048576); // 896x4096 fp8 = 3.5MB

  prep<<<256, 256, 0, stream>>>(logits, hash, teacher, Pq, QT, qpart, rowexp,
                                possum, cntw, dtot);
  // 28 G-blocks (C=Q^T Q, 7x7 triangle) + 1024 S-blocks (32x32 full square)
  mega<<<1052, 256, 0, stream>>>(Pq, QT, mask, rowexp, possum, cntw, dtot);
  finalize<<<1, 1024, 0, stream>>>(rowexp, possum, cntw, qpart, dtot, out);
}